// Round 15
// baseline (43.828 us; speedup 1.0000x reference)
//
#include <hip/hip_runtime.h>
#include <math.h>

#define G_ 320
#define N_ 1000
#define T_ 10
#define C_ 96
#define E_ 8000
#define QN 250          // nodes per quarter (4 quarters per graph)
#define CAP 2816        // slot capacity per quarter (mean ~2250, +14 sigma)
#define NTB 129         // ratio-table points per half (128 intervals)

// Single fused kernel, TWO graphs per block (same quarter -> one shared CSR).
// Block = (quarter q, graph pair gy): graphs g0=2*gy, g0+1.
// out[g,n,c] = S[g,n]*Wl[c] + (bl[c]+bias[c]+pos[t,c])
// logit(u,v) = 0.6*(u*A+v*B+Cb) + big * tab[which][ratio]   (bl+br==0 path)
__global__ __launch_bounds__(256, 6) void kAll2(
        const float* __restrict__ x, const int* __restrict__ ei,
        const float* __restrict__ Wl, const float* __restrict__ bl,
        const float* __restrict__ Wr, const float* __restrict__ br,
        const float* __restrict__ att, const float* __restrict__ bias,
        float4* __restrict__ out) {
    __shared__ float xgs[2][N_];
    __shared__ int   slots[CAP];          // packed: src | (dst<<16)
    __shared__ int   cnt[256], cur[256], offsL[256];
    __shared__ float tabL[2 * NTB];
    __shared__ float Sloc[2][QN];
    __shared__ float4 wl4[C_ / 4];
    __shared__ float4 cb4[2][C_ / 4];
    __shared__ float lin4[4];             // 0.6A, 0.6B, 0.6Cb, homog flag

    const int tid = threadIdx.x;
    const int q = blockIdx.x, gy = blockIdx.y;
    const int g0 = gy * 2;
    const int lo = q * QN;
    const int t0 = g0 % T_;               // even; t1 = t0+1

    // ---- stage: issue global loads first, then VALU table work ----
    {   // both graphs' x rows (contiguous 2000 floats)
        const float4* xb = (const float4*)(x + (size_t)g0 * N_);
        ((float4*)xgs)[tid] = xb[tid];
        if (tid < 2 * N_ / 4 - 256) ((float4*)xgs)[tid + 256] = xb[tid + 256];
    }
    // register-cache the edge list (2000 int4 each of dst, src)
    int4 dreg[8], sreg[8];
    const int4* d4 = (const int4*)(ei + E_);
    const int4* s4 = (const int4*)ei;
#pragma unroll
    for (int k = 0; k < 8; k++) {
        int j = tid + k * 256;
        if (j < E_ / 4) { dreg[k] = d4[j]; sreg[k] = s4[j]; }
    }
    cnt[tid] = (tid < QN) ? 1 : 0;        // self-loop pre-count
    if (tid < 192) {                      // cb4 for both graphs
        int it = tid / C_, c = tid - it * C_;
        int tt = t0 + it;
        int k2 = c & ~1;
        float dt = __expf(-(float)k2 * (logf(10000.0f) / (float)C_));
        float ang = (float)tt * dt;
        float pe = (c & 1) ? cosf(ang) : sinf(ang);
        ((float*)cb4[it])[c] = bl[c] + bias[c] + pe;
    }
    if (tid < C_) ((float*)wl4)[tid] = Wl[tid];
    {   // lin terms (waves 0-2) + homogeneity flag (wave 3)
        int w = tid >> 6, lane = tid & 63;
        if (w < 3) {
            float s = 0.f;
            for (int i = lane; i < C_; i += 64) {
                float a = att[i];
                float m = (w == 0) ? Wl[i] : (w == 1) ? Wr[i] : (bl[i] + br[i]);
                s += a * m;
            }
            for (int off = 32; off; off >>= 1) s += __shfl_down(s, off);
            if (lane == 0) lin4[w] = 0.6f * s;
        } else {
            float m = 0.f;
            for (int i = lane; i < C_; i += 64) m = fmaxf(m, fabsf(bl[i] + br[i]));
            for (int off = 32; off; off >>= 1) m = fmaxf(m, __shfl_down(m, off));
            if (lane == 0) lin4[3] = (m == 0.f) ? 1.f : 0.f;
        }
    }
    // ratio tables: tab[0][j]=sum 0.4a|wl + t_j*wr| ; tab[1][j] roles swapped
    for (int i = tid; i < 2 * NTB; i += 256) {
        int which = (i >= NTB);
        int j = i - which * NTB;
        float tt = -1.f + (float)j * (2.f / (float)(NTB - 1));
        float s = 0.f;
        for (int c = 0; c < C_; c++) {     // uniform c -> scalar loads
            float wl = Wl[c], wr = Wr[c];
            float val = which ? fmaf(tt, wl, wr) : fmaf(tt, wr, wl);
            s = fmaf(0.4f * att[c], fabsf(val), s);
        }
        tabL[i] = s;
    }
    __syncthreads();

    // ---- count from registers ----
#pragma unroll
    for (int k = 0; k < 8; k++) {
        int j = tid + k * 256;
        if (j < E_ / 4) {
            int4 d = dreg[k];
            int r0 = d.x - lo, r1 = d.y - lo, r2 = d.z - lo, r3 = d.w - lo;
            if ((unsigned)r0 < (unsigned)QN) atomicAdd(&cnt[r0], 1);
            if ((unsigned)r1 < (unsigned)QN) atomicAdd(&cnt[r1], 1);
            if ((unsigned)r2 < (unsigned)QN) atomicAdd(&cnt[r2], 1);
            if ((unsigned)r3 < (unsigned)QN) atomicAdd(&cnt[r3], 1);
        }
    }
    __syncthreads();

    // ---- wave-0 shuffle scan over 256 counters (lane owns 4) ----
    if (tid < 64) {
        int b4 = tid * 4;
        int a0 = cnt[b4], a1 = cnt[b4 + 1], a2 = cnt[b4 + 2], a3 = cnt[b4 + 3];
        int s1 = a0 + a1, s2 = s1 + a2, s3 = s2 + a3;
        int pre = s3;
        for (int off = 1; off < 64; off <<= 1) {
            int tv = __shfl_up(pre, off);
            if (tid >= off) pre += tv;
        }
        int base = pre - s3;
        offsL[b4] = base;          cur[b4] = base;
        offsL[b4 + 1] = base + a0; cur[b4 + 1] = base + a0;
        offsL[b4 + 2] = base + s1; cur[b4 + 2] = base + s1;
        offsL[b4 + 3] = base + s2; cur[b4 + 3] = base + s2;
    }
    __syncthreads();
    const int cntE = offsL[QN];            // counters 250..255 are zero

    // ---- scatter packed ids from registers ----
#pragma unroll
    for (int k = 0; k < 8; k++) {
        int j = tid + k * 256;
        if (j < E_ / 4) {
            int4 d = dreg[k];
            int4 s = sreg[k];
#define SCAT(DD, SS) { int r = (DD) - lo;                                    \
            if ((unsigned)r < (unsigned)QN) {                                \
                int pos = atomicAdd(&cur[r], 1);                             \
                slots[pos] = (SS) | ((DD) << 16); } }
            SCAT(d.x, s.x) SCAT(d.y, s.y) SCAT(d.z, s.z) SCAT(d.w, s.w)
#undef SCAT
        }
    }
    if (tid < QN) {                        // self-loops
        int nid = lo + tid;
        int pos = atomicAdd(&cur[tid], 1);
        slots[pos] = nid | (nid << 16);
    }
    __syncthreads();

    // ---- per-node logits + online softmax, both graphs ----
    const float la = lin4[0], lb = lin4[1], lc = lin4[2];
    const bool homog = (lin4[3] != 0.f);   // uniform branch
    if (tid < QN) {
        int a = offsL[tid], b = (tid == QN - 1) ? cntE : offsL[tid + 1];
#pragma unroll 1
        for (int it = 0; it < 2; ++it) {
            const float* xx = xgs[it];
            float m = -INFINITY, den = 0.f, num = 0.f;
            if (homog) {
                for (int p = a; p < b; ++p) {
                    int sd = slots[p];
                    float uu = xx[sd & 0xFFFF], vv = xx[sd >> 16];
                    float au = fabsf(uu), av = fabsf(vv);
                    bool ub = au >= av;
                    float big = ub ? au : av;
                    float tt = (ub ? vv : uu) / (ub ? uu : vv);
                    tt = fmaxf(fminf(tt, 1.f), -1.f);     // sanitizes 0/0
                    float fi = fmaf(tt, 64.f, 64.f);      // [0,128]
                    int i0 = (int)fi; i0 = min(i0, NTB - 2);
                    float fr = fi - (float)i0;
                    int bse = ub ? 0 : NTB;
                    float ta = tabL[bse + i0], tb = tabL[bse + i0 + 1];
                    float l = fmaf(big, fmaf(fr, tb - ta, ta),
                                   fmaf(uu, la, fmaf(vv, lb, lc)));
                    float nm = fmaxf(m, l);
                    float sc = __expf(m - nm);
                    float ex = __expf(l - nm);
                    den = den * sc + ex;
                    num = fmaf(ex, uu, num * sc);
                    m = nm;
                }
            } else {
                for (int p = a; p < b; ++p) {
                    int sd = slots[p];
                    float uu = xx[sd & 0xFFFF], vv = xx[sd >> 16];
                    float a2 = 0.f;
                    for (int c = 0; c < C_; c++) {
                        float wv = fmaf(uu, Wl[c], fmaf(vv, Wr[c], bl[c] + br[c]));
                        a2 = fmaf(0.4f * att[c], fabsf(wv), a2);
                    }
                    float l = fmaf(uu, la, fmaf(vv, lb, lc)) + a2;
                    float nm = fmaxf(m, l);
                    float sc = __expf(m - nm);
                    float ex = __expf(l - nm);
                    den = den * sc + ex;
                    num = fmaf(ex, uu, num * sc);
                    m = nm;
                }
            }
            Sloc[it][tid] = num / den;
        }
    }
    __syncthreads();

    // ---- one continuous write burst: two 250x24-float4 slabs ----
#pragma unroll 1
    for (int it = 0; it < 2; ++it) {
        float4* out4 = out + (size_t)((g0 + it) * N_ + lo) * (C_ / 4);
        int node = tid / 24, c4 = tid % 24;
        const float* sl = Sloc[it];
        const float4* cb = cb4[it];
        for (int i = tid; i < QN * (C_ / 4); i += 256) {
            float s = sl[node];
            float4 wv = wl4[c4], cbv = cb[c4];
            out4[i] = make_float4(fmaf(s, wv.x, cbv.x), fmaf(s, wv.y, cbv.y),
                                  fmaf(s, wv.z, cbv.z), fmaf(s, wv.w, cbv.w));
            int c4n = c4 + 16;             // 256 = 10*24 + 16
            int carry = (c4n >= 24) ? 1 : 0;
            node += 10 + carry;
            c4 = c4n - (carry ? 24 : 0);
        }
    }
}

extern "C" void kernel_launch(void* const* d_in, const int* in_sizes, int n_in,
                              void* d_out, int out_size, void* d_ws, size_t ws_size,
                              hipStream_t stream) {
    const float* x    = (const float*)d_in[0];
    const int*   ei   = (const int*)d_in[1];
    const float* Wl   = (const float*)d_in[2];
    const float* bl   = (const float*)d_in[3];
    const float* Wr   = (const float*)d_in[4];
    const float* br   = (const float*)d_in[5];
    const float* att  = (const float*)d_in[6];
    const float* bias = (const float*)d_in[7];
    float4* out = (float4*)d_out;

    hipLaunchKernelGGL(kAll2, dim3(4, G_ / 2), dim3(256), 0, stream,
                       x, ei, Wl, bl, Wr, br, att, bias, out);
}